// Round 1
// baseline (92.485 us; speedup 1.0000x reference)
//
#include <hip/hip_runtime.h>

// ---- G(3,0,1) PGA tables, generated at compile time via bitmask blades ----
namespace ga {

// Blade order matches the Python reference:
// idx : 0=1, 1=e0, 2=e1, 3=e2, 4=e3, 5=e01, 6=e02, 7=e03, 8=e12, 9=e13,
//       10=e23, 11=e012, 12=e013, 13=e023, 14=e123, 15=e0123
constexpr unsigned MASKS[16] = {0u, 1u, 2u, 4u, 8u,
                                3u, 5u, 9u, 6u, 10u, 12u,
                                7u, 11u, 13u, 14u, 15u};

constexpr int idx_of_mask(unsigned m) {
  for (int i = 0; i < 16; ++i)
    if (MASKS[i] == m) return i;
  return -1;
}

constexpr int popc4(unsigned x) {
  int c = 0;
  for (int i = 0; i < 4; ++i) c += (x >> i) & 1u;
  return c;
}

// sign to sort concatenation [A..., B...]: (-1)^{#(a in A, b in B : a > b)}
constexpr int reorder_sign(unsigned a, unsigned b) {
  int cnt = 0;
  for (int i = 0; i < 4; ++i)
    if ((a >> i) & 1u) cnt += popc4(b & ((1u << i) - 1u));
  return (cnt & 1) ? -1 : 1;
}

struct Tab {
  float gp_s[16][16];
  int   gp_k[16][16];
  float jn_s[16][16];
  int   jn_k[16][16];
};

constexpr Tab make_tab() {
  Tab t{};
  // dual signs: dual(e_i) = msign[i] * e_{comp(i)}
  float msign[16] = {};
  for (int i = 0; i < 16; ++i) {
    unsigned a = MASKS[i];
    msign[i] = (float)reorder_sign(a, (~a) & 0xFu);
  }
  for (int i = 0; i < 16; ++i) {
    for (int j = 0; j < 16; ++j) {
      unsigned A = MASKS[i], B = MASKS[j];
      // geometric product: zero iff e0 repeats; e1..e3 square to +1
      if (A & B & 1u) {
        t.gp_s[i][j] = 0.0f; t.gp_k[i][j] = 0;
      } else {
        t.gp_s[i][j] = (float)reorder_sign(A, B);
        t.gp_k[i][j] = idx_of_mask(A ^ B);
      }
      // join: undual(dual(x) ^ dual(y)); M^-1 = M^T (signed permutation)
      unsigned Ac = (~A) & 0xFu, Bc = (~B) & 0xFu;
      if (Ac & Bc) {
        t.jn_s[i][j] = 0.0f; t.jn_k[i][j] = 0;
      } else {
        unsigned Cc = Ac | Bc;                 // wedge result in dual space
        int k = idx_of_mask((~Cc) & 0xFu);     // undual
        float s = (float)reorder_sign(Ac, Bc)  // wedge sign
                * msign[i] * msign[j]          // M[a,i] * M[b,j]
                * msign[k];                    // Minv[k,c] = M[c,k]
        t.jn_s[i][j] = s; t.jn_k[i][j] = k;
      }
    }
  }
  return t;
}

constexpr Tab TAB = make_tab();

} // namespace ga

__global__ __launch_bounds__(256)
void mv_bilinear_kernel(const float4* __restrict__ x4,
                        const float4* __restrict__ y4,
                        const float*  __restrict__ ref,
                        float4*       __restrict__ o4,
                        int npts) {
  const int p = blockIdx.x * blockDim.x + threadIdx.x;
  if (p >= npts) return;

  float xv[16], yv[16];
  {
    float4 a = x4[p * 4 + 0], b = x4[p * 4 + 1],
           c = x4[p * 4 + 2], d = x4[p * 4 + 3];
    xv[0]=a.x; xv[1]=a.y; xv[2]=a.z; xv[3]=a.w;
    xv[4]=b.x; xv[5]=b.y; xv[6]=b.z; xv[7]=b.w;
    xv[8]=c.x; xv[9]=c.y; xv[10]=c.z; xv[11]=c.w;
    xv[12]=d.x; xv[13]=d.y; xv[14]=d.z; xv[15]=d.w;
  }
  {
    float4 a = y4[p * 4 + 0], b = y4[p * 4 + 1],
           c = y4[p * 4 + 2], d = y4[p * 4 + 3];
    yv[0]=a.x; yv[1]=a.y; yv[2]=a.z; yv[3]=a.w;
    yv[4]=b.x; yv[5]=b.y; yv[6]=b.z; yv[7]=b.w;
    yv[8]=c.x; yv[9]=c.y; yv[10]=c.z; yv[11]=c.w;
    yv[12]=d.x; yv[13]=d.y; yv[14]=d.z; yv[15]=d.w;
  }
  const float r = ref[(size_t)p * 16 + 15];

  float gp[16], jn[16];
  #pragma unroll
  for (int k = 0; k < 16; ++k) { gp[k] = 0.0f; jn[k] = 0.0f; }

  // Fully unrolled: all table lookups fold to compile-time constants,
  // accumulators stay in registers (192 GP FMAs + 81 JOIN FMAs).
  #pragma unroll
  for (int i = 0; i < 16; ++i) {
    #pragma unroll
    for (int j = 0; j < 16; ++j) {
      const float gs = ga::TAB.gp_s[i][j];
      const float js = ga::TAB.jn_s[i][j];
      if (gs != 0.0f || js != 0.0f) {
        const float prod = xv[i] * yv[j];
        if (gs != 0.0f) {
          const int k = ga::TAB.gp_k[i][j];
          gp[k] = (gs > 0.0f) ? (gp[k] + prod) : (gp[k] - prod);
        }
        if (js != 0.0f) {
          const int k = ga::TAB.jn_k[i][j];
          jn[k] = (js > 0.0f) ? (jn[k] + prod) : (jn[k] - prod);
        }
      }
    }
  }

  float4* o = o4 + (size_t)p * 8;
  o[0] = make_float4(gp[0],  gp[1],  gp[2],  gp[3]);
  o[1] = make_float4(gp[4],  gp[5],  gp[6],  gp[7]);
  o[2] = make_float4(gp[8],  gp[9],  gp[10], gp[11]);
  o[3] = make_float4(gp[12], gp[13], gp[14], gp[15]);
  o[4] = make_float4(r*jn[0],  r*jn[1],  r*jn[2],  r*jn[3]);
  o[5] = make_float4(r*jn[4],  r*jn[5],  r*jn[6],  r*jn[7]);
  o[6] = make_float4(r*jn[8],  r*jn[9],  r*jn[10], r*jn[11]);
  o[7] = make_float4(r*jn[12], r*jn[13], r*jn[14], r*jn[15]);
}

extern "C" void kernel_launch(void* const* d_in, const int* in_sizes, int n_in,
                              void* d_out, int out_size, void* d_ws, size_t ws_size,
                              hipStream_t stream) {
  const float4* x4  = (const float4*)d_in[0];
  const float4* y4  = (const float4*)d_in[1];
  const float*  ref = (const float*)d_in[2];
  float4* o4 = (float4*)d_out;

  const int npts = in_sizes[0] / 16;  // B*T multivectors
  const int block = 256;
  const int grid = (npts + block - 1) / block;
  mv_bilinear_kernel<<<grid, block, 0, stream>>>(x4, y4, ref, o4, npts);
}

// Round 2
// 52.411 us; speedup vs baseline: 1.7646x; 1.7646x over previous
//
#include <hip/hip_runtime.h>

// ---- G(3,0,1) PGA tables, generated at compile time via bitmask blades ----
namespace ga {

// Blade order matches the Python reference:
// idx : 0=1, 1=e0, 2=e1, 3=e2, 4=e3, 5=e01, 6=e02, 7=e03, 8=e12, 9=e13,
//       10=e23, 11=e012, 12=e013, 13=e023, 14=e123, 15=e0123
constexpr unsigned MASKS[16] = {0u, 1u, 2u, 4u, 8u,
                                3u, 5u, 9u, 6u, 10u, 12u,
                                7u, 11u, 13u, 14u, 15u};

constexpr int idx_of_mask(unsigned m) {
  for (int i = 0; i < 16; ++i)
    if (MASKS[i] == m) return i;
  return -1;
}

constexpr int popc4(unsigned x) {
  int c = 0;
  for (int i = 0; i < 4; ++i) c += (x >> i) & 1u;
  return c;
}

// sign to sort concatenation [A..., B...]: (-1)^{#(a in A, b in B : a > b)}
constexpr int reorder_sign(unsigned a, unsigned b) {
  int cnt = 0;
  for (int i = 0; i < 4; ++i)
    if ((a >> i) & 1u) cnt += popc4(b & ((1u << i) - 1u));
  return (cnt & 1) ? -1 : 1;
}

struct Tab {
  float gp_s[16][16];
  int   gp_k[16][16];
  float jn_s[16][16];
  int   jn_k[16][16];
};

constexpr Tab make_tab() {
  Tab t{};
  float msign[16] = {};
  for (int i = 0; i < 16; ++i) {
    unsigned a = MASKS[i];
    msign[i] = (float)reorder_sign(a, (~a) & 0xFu);
  }
  for (int i = 0; i < 16; ++i) {
    for (int j = 0; j < 16; ++j) {
      unsigned A = MASKS[i], B = MASKS[j];
      if (A & B & 1u) {  // e0 repeats -> 0 (degenerate metric)
        t.gp_s[i][j] = 0.0f; t.gp_k[i][j] = 0;
      } else {
        t.gp_s[i][j] = (float)reorder_sign(A, B);
        t.gp_k[i][j] = idx_of_mask(A ^ B);
      }
      unsigned Ac = (~A) & 0xFu, Bc = (~B) & 0xFu;
      if (Ac & Bc) {
        t.jn_s[i][j] = 0.0f; t.jn_k[i][j] = 0;
      } else {
        unsigned Cc = Ac | Bc;
        int k = idx_of_mask((~Cc) & 0xFu);
        float s = (float)reorder_sign(Ac, Bc)
                * msign[i] * msign[j]
                * msign[k];
        t.jn_s[i][j] = s; t.jn_k[i][j] = k;
      }
    }
  }
  return t;
}

constexpr Tab TAB = make_tab();

} // namespace ga

typedef float f32x4 __attribute__((ext_vector_type(4)));

__global__ __launch_bounds__(256)
void mv_bilinear_kernel(const float4* __restrict__ x4,
                        const float4* __restrict__ y4,
                        const float*  __restrict__ ref,
                        float4*       __restrict__ o4,
                        int npts) {
  // 256 points/block * 8 float4 out = 32 KB staging
  __shared__ f32x4 sout[2048];

  const int t = threadIdx.x;
  const int pbase = blockIdx.x * 256;
  const int p = pbase + t;
  const bool act = p < npts;

  float xv[16], yv[16];
  float r = 0.0f;
  if (act) {
    float4 a = x4[p * 4 + 0], b = x4[p * 4 + 1],
           c = x4[p * 4 + 2], d = x4[p * 4 + 3];
    xv[0]=a.x; xv[1]=a.y; xv[2]=a.z; xv[3]=a.w;
    xv[4]=b.x; xv[5]=b.y; xv[6]=b.z; xv[7]=b.w;
    xv[8]=c.x; xv[9]=c.y; xv[10]=c.z; xv[11]=c.w;
    xv[12]=d.x; xv[13]=d.y; xv[14]=d.z; xv[15]=d.w;
    a = y4[p * 4 + 0]; b = y4[p * 4 + 1];
    c = y4[p * 4 + 2]; d = y4[p * 4 + 3];
    yv[0]=a.x; yv[1]=a.y; yv[2]=a.z; yv[3]=a.w;
    yv[4]=b.x; yv[5]=b.y; yv[6]=b.z; yv[7]=b.w;
    yv[8]=c.x; yv[9]=c.y; yv[10]=c.z; yv[11]=c.w;
    yv[12]=d.x; yv[13]=d.y; yv[14]=d.z; yv[15]=d.w;
    r = ref[(size_t)p * 16 + 15];
  } else {
    #pragma unroll
    for (int k = 0; k < 16; ++k) { xv[k] = 0.0f; yv[k] = 0.0f; }
  }

  float gp[16], jn[16];
  #pragma unroll
  for (int k = 0; k < 16; ++k) { gp[k] = 0.0f; jn[k] = 0.0f; }

  // Fully unrolled sparse bilinear: all table entries fold to literals.
  #pragma unroll
  for (int i = 0; i < 16; ++i) {
    #pragma unroll
    for (int j = 0; j < 16; ++j) {
      const float gs = ga::TAB.gp_s[i][j];
      const float js = ga::TAB.jn_s[i][j];
      if (gs != 0.0f || js != 0.0f) {
        const float prod = xv[i] * yv[j];
        if (gs != 0.0f) {
          const int k = ga::TAB.gp_k[i][j];
          gp[k] = (gs > 0.0f) ? (gp[k] + prod) : (gp[k] - prod);
        }
        if (js != 0.0f) {
          const int k = ga::TAB.jn_k[i][j];
          jn[k] = (js > 0.0f) ? (jn[k] + prod) : (jn[k] - prod);
        }
      }
    }
  }

  // Stage this point's 8 output float4s into LDS, XOR-swizzled on the
  // float4 index so both the write and the transposed read sit at the
  // b128 bank floor (no conflicts beyond the 8-cycle minimum).
  {
    f32x4 v[8];
    v[0] = (f32x4){gp[0],  gp[1],  gp[2],  gp[3]};
    v[1] = (f32x4){gp[4],  gp[5],  gp[6],  gp[7]};
    v[2] = (f32x4){gp[8],  gp[9],  gp[10], gp[11]};
    v[3] = (f32x4){gp[12], gp[13], gp[14], gp[15]};
    v[4] = (f32x4){r*jn[0],  r*jn[1],  r*jn[2],  r*jn[3]};
    v[5] = (f32x4){r*jn[4],  r*jn[5],  r*jn[6],  r*jn[7]};
    v[6] = (f32x4){r*jn[8],  r*jn[9],  r*jn[10], r*jn[11]};
    v[7] = (f32x4){r*jn[12], r*jn[13], r*jn[14], r*jn[15]};
    #pragma unroll
    for (int c = 0; c < 8; ++c)
      sout[t * 8 + (c ^ (t & 7))] = v[c];
  }
  __syncthreads();

  // Coalesced, nontemporal writeback: each store instruction covers a
  // contiguous 1 KiB (8 full 128B lines), each line written exactly once.
  // NT keeps the 128 MiB streaming output from evicting the 192 MiB
  // input set out of Infinity Cache.
  const size_t gbase = (size_t)pbase * 8;
  #pragma unroll
  for (int k = 0; k < 8; ++k) {
    const int f = t + 256 * k;            // float4 index within block tile
    const int pl = f >> 3;                 // local point
    const int c  = f & 7;                  // float4 slot within point
    if (pbase + pl < npts) {
      f32x4 v = sout[pl * 8 + (c ^ (pl & 7))];
      __builtin_nontemporal_store(v, (f32x4*)&o4[gbase + f]);
    }
  }
}

extern "C" void kernel_launch(void* const* d_in, const int* in_sizes, int n_in,
                              void* d_out, int out_size, void* d_ws, size_t ws_size,
                              hipStream_t stream) {
  const float4* x4  = (const float4*)d_in[0];
  const float4* y4  = (const float4*)d_in[1];
  const float*  ref = (const float*)d_in[2];
  float4* o4 = (float4*)d_out;

  const int npts = in_sizes[0] / 16;  // B*T multivectors
  const int block = 256;
  const int grid = (npts + block - 1) / block;
  mv_bilinear_kernel<<<grid, block, 0, stream>>>(x4, y4, ref, o4, npts);
}